// Round 4
// baseline (813.192 us; speedup 1.0000x reference)
//
#include <hip/hip_runtime.h>

#define HH 181
#define WW 360
#define NPIX (HH*WW)        // 65160
#define NCH 16
#define NHID 256
#define NPIX16 (NCH*NPIX)   // 1042560
#define EPITOL 1e-5f
#define NTERMS 19
#define NBLK 512            // 2 blocks/CU launched; capacity 4/CU (VGPR<=128) -> safe
#define PPT 8               // 512*256*8 = 1048576 >= NPIX16

// 6th-order upwind RHS at one (channel,h,w) point; geo-cyclic padding via
// index math (lon: cyclic wrap; lat: pole mirror with +180deg column flip).
__device__ __forceinline__ float rhs_point(const float* __restrict__ qo,
                                           float uu, float vv,
                                           float inv_dlon, float inv_dlat,
                                           int h, int w, int wf) {
    const float cp0 = -2.0f/60.0f, cp1 = 15.0f/60.0f, cp2 = -60.0f/60.0f,
                cp3 = 20.0f/60.0f, cp4 = 30.0f/60.0f, cp5 = -3.0f/60.0f;
    const float cn0 =  3.0f/60.0f, cn1 = -30.0f/60.0f, cn2 = -20.0f/60.0f,
                cn3 = 60.0f/60.0f, cn4 = -15.0f/60.0f, cn5 =  2.0f/60.0f;

    const float* row = qo + h * WW;
    float t[7];
#pragma unroll
    for (int i = 0; i < 7; ++i) {
        int wm = w + i - 3;
        wm = (wm < 0) ? wm + WW : wm;
        wm = (wm >= WW) ? wm - WW : wm;
        t[i] = row[wm];
    }
    float dpl = cp0*t[0] + cp1*t[1] + cp2*t[2] + cp3*t[3] + cp4*t[4] + cp5*t[5];
    float dnl = cn0*t[1] + cn1*t[2] + cn2*t[3] + cn3*t[4] + cn4*t[5] + cn5*t[6];

    float s[7];
#pragma unroll
    for (int i = 0; i < 7; ++i) {
        int rr = h + i - 3;
        int wc = w;
        if (rr < 0)            { rr = -1 - rr;        wc = wf; }
        else if (rr > HH - 1)  { rr = 2*HH - 1 - rr;  wc = wf; }
        s[i] = qo[rr * WW + wc];
    }
    float dpa = cp0*s[0] + cp1*s[1] + cp2*s[2] + cp3*s[3] + cp4*s[4] + cp5*s[5];
    float dna = cn0*s[1] + cn1*s[2] + cn2*s[3] + cn3*s[4] + cn4*s[5] + cn5*s[6];

    float dql = (uu > 0.0f ? dpl : dnl) * inv_dlon;
    float dqa = (vv > 0.0f ? dpa : dna) * inv_dlat;
    return -uu * dql - vv * dqa;
}

// Grid barrier, no contended atomics: each block release-stores its own slot;
// block 0 polls all slots then release-stores gen; others acquire-spin on gen.
// Spin caps turn a (non-)residency failure into a wrong answer, not a hang.
__device__ __forceinline__ void grid_barrier(unsigned* __restrict__ gen,
                                             unsigned* __restrict__ arrive,
                                             unsigned target) {
    __syncthreads();   // all block work issued & drained (vmcnt(0) before s_barrier)
    if (blockIdx.x == 0) {
        if (threadIdx.x == 0)
            __hip_atomic_store(&arrive[0], target, __ATOMIC_RELEASE,
                               __HIP_MEMORY_SCOPE_AGENT);
        int guard = 0;
        bool ok;
        do {
            ok = true;
#pragma unroll
            for (int j = 0; j < NBLK / 256; ++j) {
                unsigned a = __hip_atomic_load(&arrive[threadIdx.x + j * 256],
                                               __ATOMIC_ACQUIRE,
                                               __HIP_MEMORY_SCOPE_AGENT);
                ok = ok && (a >= target);
            }
        } while (!__syncthreads_and(ok) && ++guard < (1 << 22));
        if (threadIdx.x == 0)
            __hip_atomic_store(gen, target, __ATOMIC_RELEASE,
                               __HIP_MEMORY_SCOPE_AGENT);
    } else {
        if (threadIdx.x == 0) {
            __hip_atomic_store(&arrive[blockIdx.x], target, __ATOMIC_RELEASE,
                               __HIP_MEMORY_SCOPE_AGENT);
            int guard = 0;
            while (__hip_atomic_load(gen, __ATOMIC_ACQUIRE,
                                     __HIP_MEMORY_SCOPE_AGENT) < target &&
                   ++guard < (1 << 22))
                __builtin_amdgcn_s_sleep(2);
        }
        __syncthreads();
    }
}

// K0: transpose W_down + zero barrier/flag control words.
__global__ __launch_bounds__(256) void tr_kernel(const float* __restrict__ Wd,
                                                 float* __restrict__ WdT,
                                                 unsigned* __restrict__ ctrl) {
    int i = blockIdx.x * 256 + threadIdx.x;
    if (i < 1024) ctrl[i] = 0u;
    if (i < NCH * NHID) {
        int o = i / NHID, c = i - o * NHID;
        WdT[c * NCH + o] = Wd[i];
    }
}

// K1: q[o,pix] = sum_c WdT[c,o] * hidden[c,pix] + b_down[o]
__global__ __launch_bounds__(256) void down_kernel(const float* __restrict__ hid,
                                                   const float* __restrict__ WdT,
                                                   const float* __restrict__ b_down,
                                                   float* __restrict__ q) {
    int pix = blockIdx.x * 256 + threadIdx.x;
    if (pix >= NPIX) return;
    float acc[NCH];
#pragma unroll
    for (int o = 0; o < NCH; ++o) acc[o] = b_down[o];
#pragma unroll 8
    for (int c = 0; c < NHID; ++c) {
        float hv = hid[c * NPIX + pix];
#pragma unroll
        for (int o = 0; o < NCH; ++o) acc[o] += WdT[c * NCH + o] * hv;
    }
#pragma unroll
    for (int o = 0; o < NCH; ++o) q[o * NPIX + pix] = acc[o];
}

// K2 (persistent, normal launch): F_n + full phi1 series + dwc epilogue.
// ctrl layout: [0..31] flags, [64] gen, [128..639] arrive slots.
__global__ __launch_bounds__(256, 4) void phi1_kernel(
        const float* __restrict__ q,
        const float* __restrict__ u,
        const float* __restrict__ v,
        const float* __restrict__ dt_p,
        const float* __restrict__ dlon_p,
        const float* __restrict__ dlat_p,
        float* __restrict__ t0,
        float* __restrict__ t1,
        float* __restrict__ dwc,
        const float* __restrict__ dw,
        const float* __restrict__ db,
        unsigned* __restrict__ ctrl) {
    unsigned* flags  = ctrl;
    unsigned* gen    = ctrl + 64;
    unsigned* arrive = ctrl + 128;

    const float inv_dlon = 1.0f / dlon_p[0];
    const float inv_dlat = 1.0f / dlat_p[0];
    const float dt = dt_p[0];

    const int base = blockIdx.x * (256 * PPT) + threadIdx.x;
    int chb[PPT], h_[PPT], w_[PPT], wf_[PPT];
    float uu[PPT], vv[PPT], res[PPT];
#pragma unroll
    for (int i = 0; i < PPT; ++i) {
        int idx = base + i * 256;
        int id = (idx < NPIX16) ? idx : 0;
        int o = id / NPIX, pix = id - o * NPIX;
        int h = pix / WW, w = pix - h * WW;
        chb[i] = o * NPIX; h_[i] = h; w_[i] = w;
        wf_[i] = (w >= WW / 2) ? (w - WW / 2) : (w + WW / 2);
        uu[i] = u[id]; vv[i] = v[id];
        res[i] = 0.0f;
    }

    __shared__ float wmax[4];
    __shared__ unsigned sflag;

    // pass 0: F_n = rhs(q); term0 = result = F_n
#pragma unroll
    for (int i = 0; i < PPT; ++i) {
        int idx = base + i * 256;
        if (idx >= NPIX16) continue;
        float val = rhs_point(q + chb[i], uu[i], vv[i], inv_dlon, inv_dlat,
                              h_[i], w_[i], wf_[i]);
        res[i] = val;
        t0[idx] = val;
    }
    unsigned bar = 1;
    grid_barrier(gen, arrive, bar); ++bar;

    const float* cur = t0;
    float* nxt = t1;
    for (int k = 1; k <= NTERMS; ++k) {
        if (k >= 2) {
            if (threadIdx.x == 0)
                sflag = __hip_atomic_load(&flags[k - 1], __ATOMIC_RELAXED,
                                          __HIP_MEMORY_SCOPE_AGENT);
            __syncthreads();
            if (sflag == 0u) break;   // same value grid-wide: uniform break
        }
        const float scale = dt / ((float)k + 1.0f);
        float m = 0.0f;
#pragma unroll
        for (int i = 0; i < PPT; ++i) {
            int idx = base + i * 256;
            if (idx >= NPIX16) continue;
            float nt = rhs_point(cur + chb[i], uu[i], vv[i], inv_dlon, inv_dlat,
                                 h_[i], w_[i], wf_[i]) * scale;
            nxt[idx] = nt;
            res[i] += nt;
            m = fmaxf(m, fabsf(nt));
        }
#pragma unroll
        for (int s = 32; s >= 1; s >>= 1) m = fmaxf(m, __shfl_xor(m, s));
        if ((threadIdx.x & 63) == 0) wmax[threadIdx.x >> 6] = m;
        __syncthreads();
        if (threadIdx.x == 0) {
            float bm = fmaxf(fmaxf(wmax[0], wmax[1]), fmaxf(wmax[2], wmax[3]));
            if (bm >= EPITOL)
                __hip_atomic_store(&flags[k], 1u, __ATOMIC_RELAXED,
                                   __HIP_MEMORY_SCOPE_AGENT);   // published by barrier
        }
        grid_barrier(gen, arrive, bar); ++bar;
        const float* tmp = cur; cur = nxt; nxt = (float*)tmp;
    }

    // epilogue: dwc = (q + result*dt)*dw[o] + db[o]   (pointwise, no cross-block dep)
#pragma unroll
    for (int i = 0; i < PPT; ++i) {
        int idx = base + i * 256;
        if (idx >= NPIX16) continue;
        int o = idx / NPIX;
        float upd = q[idx] + res[i] * dt;
        dwc[idx] = upd * dw[o] + db[o];
    }
}

// K3: out[c,pix] = sum_o W_up[c,o]*dwc[o,pix] + b_up[c]; 8 chunks of 32 channels.
__global__ __launch_bounds__(256) void up_kernel(const float* __restrict__ dwc,
                                                 const float* __restrict__ Wu,
                                                 const float* __restrict__ b_up,
                                                 float* __restrict__ out) {
    int pix = blockIdx.x * 256 + threadIdx.x;
    if (pix >= NPIX) return;
    int c0 = blockIdx.y * 32;
    float d[NCH];
#pragma unroll
    for (int o = 0; o < NCH; ++o) d[o] = dwc[o * NPIX + pix];
#pragma unroll 4
    for (int cc = 0; cc < 32; ++cc) {
        int c = c0 + cc;
        float a = b_up[c];
#pragma unroll
        for (int o = 0; o < NCH; ++o) a += Wu[c * NCH + o] * d[o];
        out[c * NPIX + pix] = a;
    }
}

extern "C" void kernel_launch(void* const* d_in, const int* in_sizes, int n_in,
                              void* d_out, int out_size, void* d_ws, size_t ws_size,
                              hipStream_t stream) {
    const float* hidden = (const float*)d_in[0];   // (1,256,181,360)
    const float* u      = (const float*)d_in[1];   // (1,16,181,360)
    const float* v      = (const float*)d_in[2];   // (1,16,181,360)
    const float* dt_p   = (const float*)d_in[3];   // scalar
    const float* dlat_p = (const float*)d_in[4];   // scalar
    const float* dlon_p = (const float*)d_in[5];   // scalar
    const float* W_down = (const float*)d_in[6];   // (16,256)
    const float* b_down = (const float*)d_in[7];   // (16,)
    const float* dw     = (const float*)d_in[8];   // (16,)
    const float* db     = (const float*)d_in[9];   // (16,)
    const float* W_up   = (const float*)d_in[10];  // (256,16)
    const float* b_up   = (const float*)d_in[11];  // (256,)
    float* out = (float*)d_out;

    float* ws = (float*)d_ws;
    float* q    = ws;
    float* t0   = ws + (size_t)NPIX16;
    float* t1   = ws + (size_t)2 * NPIX16;
    float* dwcb = ws + (size_t)3 * NPIX16;
    float* WdT  = ws + (size_t)4 * NPIX16;
    unsigned* ctrl = (unsigned*)(ws + (size_t)4 * NPIX16 + NCH * NHID);

    const int nbp = (NPIX + 255) / 256;   // 255

    tr_kernel<<<(NCH * NHID + 255) / 256, 256, 0, stream>>>(W_down, WdT, ctrl);
    down_kernel<<<nbp, 256, 0, stream>>>(hidden, WdT, b_down, q);
    phi1_kernel<<<NBLK, 256, 0, stream>>>(q, u, v, dt_p, dlon_p, dlat_p,
                                          t0, t1, dwcb, dw, db, ctrl);
    up_kernel<<<dim3(nbp, 8), 256, 0, stream>>>(dwcb, W_up, b_up, out);
}

// Round 5
// 746.960 us; speedup vs baseline: 1.0887x; 1.0887x over previous
//
#include <hip/hip_runtime.h>

#define HH 181
#define WW 360
#define NPIX (HH*WW)        // 65160
#define NCH 16
#define NHID 256
#define NPIX16 (NCH*NPIX)   // 1042560
#define EPITOL 1e-5f
#define NTERMS 19
#define NBLK 512            // 2 blocks/CU launched; capacity 4/CU (VGPR<=128) -> safe
#define PPT 8               // 512*256*8 = 1048576 >= NPIX16

// 6th-order upwind RHS at one (channel,h,w) point; geo-cyclic padding via
// index math (lon: cyclic wrap; lat: pole mirror with +180deg column flip).
__device__ __forceinline__ float rhs_point(const float* __restrict__ qo,
                                           float uu, float vv,
                                           float inv_dlon, float inv_dlat,
                                           int h, int w, int wf) {
    const float cp0 = -2.0f/60.0f, cp1 = 15.0f/60.0f, cp2 = -60.0f/60.0f,
                cp3 = 20.0f/60.0f, cp4 = 30.0f/60.0f, cp5 = -3.0f/60.0f;
    const float cn0 =  3.0f/60.0f, cn1 = -30.0f/60.0f, cn2 = -20.0f/60.0f,
                cn3 = 60.0f/60.0f, cn4 = -15.0f/60.0f, cn5 =  2.0f/60.0f;

    const float* row = qo + h * WW;
    float t[7];
#pragma unroll
    for (int i = 0; i < 7; ++i) {
        int wm = w + i - 3;
        wm = (wm < 0) ? wm + WW : wm;
        wm = (wm >= WW) ? wm - WW : wm;
        t[i] = row[wm];
    }
    float dpl = cp0*t[0] + cp1*t[1] + cp2*t[2] + cp3*t[3] + cp4*t[4] + cp5*t[5];
    float dnl = cn0*t[1] + cn1*t[2] + cn2*t[3] + cn3*t[4] + cn4*t[5] + cn5*t[6];

    float s[7];
#pragma unroll
    for (int i = 0; i < 7; ++i) {
        int rr = h + i - 3;
        int wc = w;
        if (rr < 0)            { rr = -1 - rr;        wc = wf; }
        else if (rr > HH - 1)  { rr = 2*HH - 1 - rr;  wc = wf; }
        s[i] = qo[rr * WW + wc];
    }
    float dpa = cp0*s[0] + cp1*s[1] + cp2*s[2] + cp3*s[3] + cp4*s[4] + cp5*s[5];
    float dna = cn0*s[1] + cn1*s[2] + cn2*s[3] + cn3*s[4] + cn4*s[5] + cn5*s[6];

    float dql = (uu > 0.0f ? dpl : dnl) * inv_dlon;
    float dqa = (vv > 0.0f ? dpa : dna) * inv_dlat;
    return -uu * dql - vv * dqa;
}

// Grid barrier. CRITICAL: spin with RELAXED agent-scope loads (they reach the
// coherence point but emit NO buffer_inv). Exactly one __threadfence() per
// block AFTER the spin succeeds does the acquire-side L1/L2 invalidate.
// (Round-4 lesson: ACQUIRE loads in the spin loop = one full L2 invalidate
// per poll iteration -> 529 MB HBM refetch, 818 us.)
// Release stores on arrive/gen writeback dirty lines (data -> L3).
// Spin guards turn a residency failure into a wrong answer, not a hang.
__device__ __forceinline__ void grid_barrier(unsigned* __restrict__ gen,
                                             unsigned* __restrict__ arrive,
                                             unsigned target) {
    __syncthreads();   // all block work issued & drained before arrive store
    if (blockIdx.x == 0) {
        if (threadIdx.x == 0)
            __hip_atomic_store(&arrive[0], target, __ATOMIC_RELEASE,
                               __HIP_MEMORY_SCOPE_AGENT);
        int guard = 0;
        bool ok;
        do {
            ok = true;
#pragma unroll
            for (int j = 0; j < NBLK / 256; ++j) {
                unsigned a = __hip_atomic_load(&arrive[threadIdx.x + j * 256],
                                               __ATOMIC_RELAXED,
                                               __HIP_MEMORY_SCOPE_AGENT);
                ok = ok && (a >= target);
            }
        } while (!__syncthreads_and(ok) && ++guard < (1 << 22));
        if (threadIdx.x == 0)
            __hip_atomic_store(gen, target, __ATOMIC_RELEASE,
                               __HIP_MEMORY_SCOPE_AGENT);
    } else {
        if (threadIdx.x == 0) {
            __hip_atomic_store(&arrive[blockIdx.x], target, __ATOMIC_RELEASE,
                               __HIP_MEMORY_SCOPE_AGENT);
            int guard = 0;
            while (__hip_atomic_load(gen, __ATOMIC_RELAXED,
                                     __HIP_MEMORY_SCOPE_AGENT) < target &&
                   ++guard < (1 << 24))
                __builtin_amdgcn_s_sleep(2);
        }
        __syncthreads();
    }
    __threadfence();   // single acquire-side invalidate; L2 stays warm otherwise
}

// K0: transpose W_down + zero barrier/flag control words.
__global__ __launch_bounds__(256) void tr_kernel(const float* __restrict__ Wd,
                                                 float* __restrict__ WdT,
                                                 unsigned* __restrict__ ctrl) {
    int i = blockIdx.x * 256 + threadIdx.x;
    if (i < 1024) ctrl[i] = 0u;
    if (i < NCH * NHID) {
        int o = i / NHID, c = i - o * NHID;
        WdT[c * NCH + o] = Wd[i];
    }
}

// K1: q[o,pix] = sum_c WdT[c,o] * hidden[c,pix] + b_down[o]
__global__ __launch_bounds__(256) void down_kernel(const float* __restrict__ hid,
                                                   const float* __restrict__ WdT,
                                                   const float* __restrict__ b_down,
                                                   float* __restrict__ q) {
    int pix = blockIdx.x * 256 + threadIdx.x;
    if (pix >= NPIX) return;
    float acc[NCH];
#pragma unroll
    for (int o = 0; o < NCH; ++o) acc[o] = b_down[o];
#pragma unroll 8
    for (int c = 0; c < NHID; ++c) {
        float hv = hid[c * NPIX + pix];
#pragma unroll
        for (int o = 0; o < NCH; ++o) acc[o] += WdT[c * NCH + o] * hv;
    }
#pragma unroll
    for (int o = 0; o < NCH; ++o) q[o * NPIX + pix] = acc[o];
}

// K2 (persistent, normal launch): F_n + full phi1 series + dwc epilogue.
// ctrl layout: [0..31] flags, [64] gen, [128..639] arrive slots.
__global__ __launch_bounds__(256, 4) void phi1_kernel(
        const float* __restrict__ q,
        const float* __restrict__ u,
        const float* __restrict__ v,
        const float* __restrict__ dt_p,
        const float* __restrict__ dlon_p,
        const float* __restrict__ dlat_p,
        float* __restrict__ t0,
        float* __restrict__ t1,
        float* __restrict__ dwc,
        const float* __restrict__ dw,
        const float* __restrict__ db,
        unsigned* __restrict__ ctrl) {
    unsigned* flags  = ctrl;
    unsigned* gen    = ctrl + 64;
    unsigned* arrive = ctrl + 128;

    const float inv_dlon = 1.0f / dlon_p[0];
    const float inv_dlat = 1.0f / dlat_p[0];
    const float dt = dt_p[0];

    const int base = blockIdx.x * (256 * PPT) + threadIdx.x;
    int chb[PPT], h_[PPT], w_[PPT], wf_[PPT];
    float uu[PPT], vv[PPT], res[PPT];
#pragma unroll
    for (int i = 0; i < PPT; ++i) {
        int idx = base + i * 256;
        int id = (idx < NPIX16) ? idx : 0;
        int o = id / NPIX, pix = id - o * NPIX;
        int h = pix / WW, w = pix - h * WW;
        chb[i] = o * NPIX; h_[i] = h; w_[i] = w;
        wf_[i] = (w >= WW / 2) ? (w - WW / 2) : (w + WW / 2);
        uu[i] = u[id]; vv[i] = v[id];
        res[i] = 0.0f;
    }

    __shared__ float wmax[4];
    __shared__ unsigned sflag;

    // pass 0: F_n = rhs(q); term0 = result = F_n
#pragma unroll
    for (int i = 0; i < PPT; ++i) {
        int idx = base + i * 256;
        if (idx >= NPIX16) continue;
        float val = rhs_point(q + chb[i], uu[i], vv[i], inv_dlon, inv_dlat,
                              h_[i], w_[i], wf_[i]);
        res[i] = val;
        t0[idx] = val;
    }
    unsigned bar = 1;
    grid_barrier(gen, arrive, bar); ++bar;

    const float* cur = t0;
    float* nxt = t1;
    for (int k = 1; k <= NTERMS; ++k) {
        if (k >= 2) {
            if (threadIdx.x == 0)
                sflag = __hip_atomic_load(&flags[k - 1], __ATOMIC_RELAXED,
                                          __HIP_MEMORY_SCOPE_AGENT);
            __syncthreads();
            if (sflag == 0u) break;   // same value grid-wide: uniform break
        }
        const float scale = dt / ((float)k + 1.0f);
        float m = 0.0f;
#pragma unroll
        for (int i = 0; i < PPT; ++i) {
            int idx = base + i * 256;
            if (idx >= NPIX16) continue;
            float nt = rhs_point(cur + chb[i], uu[i], vv[i], inv_dlon, inv_dlat,
                                 h_[i], w_[i], wf_[i]) * scale;
            nxt[idx] = nt;
            res[i] += nt;
            m = fmaxf(m, fabsf(nt));
        }
#pragma unroll
        for (int s = 32; s >= 1; s >>= 1) m = fmaxf(m, __shfl_xor(m, s));
        if ((threadIdx.x & 63) == 0) wmax[threadIdx.x >> 6] = m;
        __syncthreads();
        if (threadIdx.x == 0) {
            float bm = fmaxf(fmaxf(wmax[0], wmax[1]), fmaxf(wmax[2], wmax[3]));
            if (bm >= EPITOL)
                __hip_atomic_store(&flags[k], 1u, __ATOMIC_RELAXED,
                                   __HIP_MEMORY_SCOPE_AGENT);   // published by barrier
        }
        grid_barrier(gen, arrive, bar); ++bar;
        const float* tmp = cur; cur = nxt; nxt = (float*)tmp;
    }

    // epilogue: dwc = (q + result*dt)*dw[o] + db[o]   (pointwise, no cross-block dep)
#pragma unroll
    for (int i = 0; i < PPT; ++i) {
        int idx = base + i * 256;
        if (idx >= NPIX16) continue;
        int o = idx / NPIX;
        float upd = q[idx] + res[i] * dt;
        dwc[idx] = upd * dw[o] + db[o];
    }
}

// K3: out[c,pix] = sum_o W_up[c,o]*dwc[o,pix] + b_up[c]; 8 chunks of 32 channels.
__global__ __launch_bounds__(256) void up_kernel(const float* __restrict__ dwc,
                                                 const float* __restrict__ Wu,
                                                 const float* __restrict__ b_up,
                                                 float* __restrict__ out) {
    int pix = blockIdx.x * 256 + threadIdx.x;
    if (pix >= NPIX) return;
    int c0 = blockIdx.y * 32;
    float d[NCH];
#pragma unroll
    for (int o = 0; o < NCH; ++o) d[o] = dwc[o * NPIX + pix];
#pragma unroll 4
    for (int cc = 0; cc < 32; ++cc) {
        int c = c0 + cc;
        float a = b_up[c];
#pragma unroll
        for (int o = 0; o < NCH; ++o) a += Wu[c * NCH + o] * d[o];
        out[c * NPIX + pix] = a;
    }
}

extern "C" void kernel_launch(void* const* d_in, const int* in_sizes, int n_in,
                              void* d_out, int out_size, void* d_ws, size_t ws_size,
                              hipStream_t stream) {
    const float* hidden = (const float*)d_in[0];   // (1,256,181,360)
    const float* u      = (const float*)d_in[1];   // (1,16,181,360)
    const float* v      = (const float*)d_in[2];   // (1,16,181,360)
    const float* dt_p   = (const float*)d_in[3];   // scalar
    const float* dlat_p = (const float*)d_in[4];   // scalar
    const float* dlon_p = (const float*)d_in[5];   // scalar
    const float* W_down = (const float*)d_in[6];   // (16,256)
    const float* b_down = (const float*)d_in[7];   // (16,)
    const float* dw     = (const float*)d_in[8];   // (16,)
    const float* db     = (const float*)d_in[9];   // (16,)
    const float* W_up   = (const float*)d_in[10];  // (256,16)
    const float* b_up   = (const float*)d_in[11];  // (256,)
    float* out = (float*)d_out;

    float* ws = (float*)d_ws;
    float* q    = ws;
    float* t0   = ws + (size_t)NPIX16;
    float* t1   = ws + (size_t)2 * NPIX16;
    float* dwcb = ws + (size_t)3 * NPIX16;
    float* WdT  = ws + (size_t)4 * NPIX16;
    unsigned* ctrl = (unsigned*)(ws + (size_t)4 * NPIX16 + NCH * NHID);

    const int nbp = (NPIX + 255) / 256;   // 255

    tr_kernel<<<(NCH * NHID + 255) / 256, 256, 0, stream>>>(W_down, WdT, ctrl);
    down_kernel<<<nbp, 256, 0, stream>>>(hidden, WdT, b_down, q);
    phi1_kernel<<<NBLK, 256, 0, stream>>>(q, u, v, dt_p, dlon_p, dlat_p,
                                          t0, t1, dwcb, dw, db, ctrl);
    up_kernel<<<dim3(nbp, 8), 256, 0, stream>>>(dwcb, W_up, b_up, out);
}

// Round 6
// 384.705 us; speedup vs baseline: 2.1138x; 1.9416x over previous
//
#include <hip/hip_runtime.h>

#define HH 181
#define WW 360
#define NPIX (HH*WW)        // 65160
#define NCH 16
#define NHID 256
#define NPIX16 (NCH*NPIX)   // 1042560
#define BH 8                // output rows per band
#define NBANDS 23           // ceil(181/8)
#define SROWS (BH + 18)     // max staged rows (3 sub-passes x halo 3 each side)
#define NACC 12             // ceil(BH*360/256)

// K0: transpose W_down (16,256) -> (256,16) for contiguous weight reads.
__global__ __launch_bounds__(256) void tr_kernel(const float* __restrict__ Wd,
                                                 float* __restrict__ WdT) {
    int i = blockIdx.x * 256 + threadIdx.x;
    if (i < NCH * NHID) {
        int o = i / NHID, c = i - o * NHID;
        WdT[c * NCH + o] = Wd[i];
    }
}

// K1: q[o,pix] = sum_c WdT[c,o] * hidden[c,pix] + b_down[o]
__global__ __launch_bounds__(256) void down_kernel(const float* __restrict__ hid,
                                                   const float* __restrict__ WdT,
                                                   const float* __restrict__ b_down,
                                                   float* __restrict__ q) {
    int pix = blockIdx.x * 256 + threadIdx.x;
    if (pix >= NPIX) return;
    float acc[NCH];
#pragma unroll
    for (int o = 0; o < NCH; ++o) acc[o] = b_down[o];
#pragma unroll 8
    for (int c = 0; c < NHID; ++c) {
        float hv = hid[c * NPIX + pix];
#pragma unroll
        for (int o = 0; o < NCH; ++o) acc[o] += WdT[c * NCH + o] * hv;
    }
#pragma unroll
    for (int o = 0; o < NCH; ++o) q[o * NPIX + pix] = acc[o];
}

// K2 (x7): nsub fused stencil passes on a full-width row band with redundant
// halo compute. No cross-block communication: halo (9 rows) + pole mirror
// (rows 0..2 / 178..180, column +180 flip) stay inside the band's LDS tile.
// Absolute pass p: term_p = rhs(term_{p-1}) * (p==0 ? 1 : dt/(p+1)).
// acc (registers) = sum of this launch's terms on the valid band; result is
// one global RMW per launch. mode: 1=first (result=acc), 0=middle (+=),
// 2=last (dwc epilogue, no term/result write).
__global__ __launch_bounds__(256) void fused_kernel(
        const float* __restrict__ tin,
        float* __restrict__ tout,
        const float* __restrict__ u,
        const float* __restrict__ v,
        const float* __restrict__ q,
        float* __restrict__ result,
        float* __restrict__ dwcb,
        const float* __restrict__ dt_p,
        const float* __restrict__ dlon_p,
        const float* __restrict__ dlat_p,
        const float* __restrict__ dw,
        const float* __restrict__ db,
        int pass_base, int nsub, int mode) {
    const float cp0 = -2.0f/60.0f, cp1 = 15.0f/60.0f, cp2 = -60.0f/60.0f,
                cp3 = 20.0f/60.0f, cp4 = 30.0f/60.0f, cp5 = -3.0f/60.0f;
    const float cn0 =  3.0f/60.0f, cn1 = -30.0f/60.0f, cn2 = -20.0f/60.0f,
                cn3 = 60.0f/60.0f, cn4 = -15.0f/60.0f, cn5 =  2.0f/60.0f;

    __shared__ float A[SROWS * WW];
    __shared__ float B[SROWS * WW];

    const int ch   = blockIdx.x / NBANDS;
    const int band = blockIdx.x - ch * NBANDS;
    const int r0   = band * BH;
    const int vr   = min(BH, HH - r0);       // valid rows (last band: 5)
    const int cb   = ch * NPIX;
    const int tid  = threadIdx.x;

    const float dt = dt_p[0];
    const float inv_dlon = 1.0f / dlon_p[0];
    const float inv_dlat = 1.0f / dlat_p[0];

    // stage input rows [glo, ghi] (genuine global rows; mirror resolved at taps)
    const int glo = max(0, r0 - 3 * nsub);
    const int ghi = min(HH - 1, r0 + vr - 1 + 3 * nsub);
    const int srows = ghi - glo + 1;
    for (int i = tid; i < srows * WW; i += 256)
        A[i] = tin[cb + (glo + i / WW) * WW + (i % WW)];

    float acc[NACC];
#pragma unroll
    for (int t = 0; t < NACC; ++t) acc[t] = 0.0f;

    float* INb = A;
    float* OUTb = B;
    int ibase = glo;      // global row of IN's row 0
    int prev_lo = glo;    // global row of previous output's row 0

    for (int j = 0; j < nsub; ++j) {
        __syncthreads();
        if (j > 0) {   // accumulate previous sub-pass output over the valid band
#pragma unroll
            for (int t = 0; t < NACC; ++t) {
                int i = tid + t * 256;
                if (i < vr * WW)
                    acc[t] += INb[(r0 + i / WW - prev_lo) * WW + (i % WW)];
            }
        }
        const int p = pass_base + j;
        const float scale = (p == 0) ? 1.0f : dt / (float)(p + 1);
        const int hlo = max(0, r0 - 3 * (nsub - 1 - j));
        const int hhi = min(HH - 1, r0 + vr - 1 + 3 * (nsub - 1 - j));
        const int rows = hhi - hlo + 1;
        for (int i = tid; i < rows * WW; i += 256) {
            const int h = hlo + i / WW;
            const int w = i % WW;
            const int wf = (w >= WW / 2) ? (w - WW / 2) : (w + WW / 2);
            // lon taps (cyclic, row h is inside IN by construction)
            const float* rowp = INb + (h - ibase) * WW;
            float tl[7];
#pragma unroll
            for (int d = 0; d < 7; ++d) {
                int wm = w + d - 3;
                wm = (wm < 0) ? wm + WW : (wm >= WW ? wm - WW : wm);
                tl[d] = rowp[wm];
            }
            float dpl = cp0*tl[0] + cp1*tl[1] + cp2*tl[2] + cp3*tl[3] + cp4*tl[4] + cp5*tl[5];
            float dnl = cn0*tl[1] + cn1*tl[2] + cn2*tl[3] + cn3*tl[4] + cn4*tl[5] + cn5*tl[6];
            // lat taps (pole mirror -> flipped column, still inside IN)
            float s[7];
#pragma unroll
            for (int d = 0; d < 7; ++d) {
                int rr = h + d - 3;
                int wc = w;
                if (rr < 0)           { rr = -1 - rr;         wc = wf; }
                else if (rr > HH - 1) { rr = 2*HH - 1 - rr;   wc = wf; }
                s[d] = INb[(rr - ibase) * WW + wc];
            }
            float dpa = cp0*s[0] + cp1*s[1] + cp2*s[2] + cp3*s[3] + cp4*s[4] + cp5*s[5];
            float dna = cn0*s[1] + cn1*s[2] + cn2*s[3] + cn3*s[4] + cn4*s[5] + cn5*s[6];

            const float uu = u[cb + h * WW + w];
            const float vv = v[cb + h * WW + w];
            float val = (-uu * ((uu > 0.0f ? dpl : dnl) * inv_dlon)
                         -vv * ((vv > 0.0f ? dpa : dna) * inv_dlat)) * scale;
            OUTb[(h - hlo) * WW + w] = val;
        }
        prev_lo = hlo;
        ibase = hlo;
        float* tmp = INb; INb = OUTb; OUTb = tmp;
    }
    __syncthreads();
    // accumulate the last sub-pass output
#pragma unroll
    for (int t = 0; t < NACC; ++t) {
        int i = tid + t * 256;
        if (i < vr * WW)
            acc[t] += INb[(r0 + i / WW - prev_lo) * WW + (i % WW)];
    }

    if (mode == 2) {
        // final launch: dwc = (q + (result+acc)*dt)*dw[ch] + db[ch]
        const float dwc_s = dw[ch], db_s = db[ch];
#pragma unroll
        for (int t = 0; t < NACC; ++t) {
            int i = tid + t * 256;
            if (i < vr * WW) {
                int g = cb + (r0 + i / WW) * WW + (i % WW);
                float tot = result[g] + acc[t];
                dwcb[g] = (q[g] + tot * dt) * dwc_s + db_s;
            }
        }
    } else {
#pragma unroll
        for (int t = 0; t < NACC; ++t) {
            int i = tid + t * 256;
            if (i < vr * WW) {
                int g = cb + (r0 + i / WW) * WW + (i % WW);
                tout[g] = INb[(r0 + i / WW - prev_lo) * WW + (i % WW)];
                if (mode == 1) result[g] = acc[t];
                else           result[g] += acc[t];
            }
        }
    }
}

// K3: out[c,pix] = sum_o W_up[c,o]*dwc[o,pix] + b_up[c]; 8 chunks of 32 channels.
__global__ __launch_bounds__(256) void up_kernel(const float* __restrict__ dwc,
                                                 const float* __restrict__ Wu,
                                                 const float* __restrict__ b_up,
                                                 float* __restrict__ out) {
    int pix = blockIdx.x * 256 + threadIdx.x;
    if (pix >= NPIX) return;
    int c0 = blockIdx.y * 32;
    float d[NCH];
#pragma unroll
    for (int o = 0; o < NCH; ++o) d[o] = dwc[o * NPIX + pix];
#pragma unroll 4
    for (int cc = 0; cc < 32; ++cc) {
        int c = c0 + cc;
        float a = b_up[c];
#pragma unroll
        for (int o = 0; o < NCH; ++o) a += Wu[c * NCH + o] * d[o];
        out[c * NPIX + pix] = a;
    }
}

extern "C" void kernel_launch(void* const* d_in, const int* in_sizes, int n_in,
                              void* d_out, int out_size, void* d_ws, size_t ws_size,
                              hipStream_t stream) {
    const float* hidden = (const float*)d_in[0];   // (1,256,181,360)
    const float* u      = (const float*)d_in[1];   // (1,16,181,360)
    const float* v      = (const float*)d_in[2];   // (1,16,181,360)
    const float* dt_p   = (const float*)d_in[3];   // scalar
    const float* dlat_p = (const float*)d_in[4];   // scalar
    const float* dlon_p = (const float*)d_in[5];   // scalar
    const float* W_down = (const float*)d_in[6];   // (16,256)
    const float* b_down = (const float*)d_in[7];   // (16,)
    const float* dw     = (const float*)d_in[8];   // (16,)
    const float* db     = (const float*)d_in[9];   // (16,)
    const float* W_up   = (const float*)d_in[10];  // (256,16)
    const float* b_up   = (const float*)d_in[11];  // (256,)
    float* out = (float*)d_out;

    float* ws = (float*)d_ws;
    float* q      = ws;
    float* T0     = ws + (size_t)NPIX16;
    float* T1     = ws + (size_t)2 * NPIX16;
    float* result = ws + (size_t)3 * NPIX16;
    float* dwcb   = ws + (size_t)4 * NPIX16;
    float* WdT    = ws + (size_t)5 * NPIX16;

    const int nbp = (NPIX + 255) / 256;   // 255
    const dim3 fg(NCH * NBANDS);          // 368 band-blocks

    tr_kernel<<<(NCH * NHID + 255) / 256, 256, 0, stream>>>(W_down, WdT);
    down_kernel<<<nbp, 256, 0, stream>>>(hidden, WdT, b_down, q);

    // passes 0..19 in 7 fused launches (6x3 + 1x2); dwc folded into the last
    fused_kernel<<<fg, 256, 0, stream>>>(q,  T0, u, v, q, result, dwcb,
                                         dt_p, dlon_p, dlat_p, dw, db, 0, 3, 1);
    fused_kernel<<<fg, 256, 0, stream>>>(T0, T1, u, v, q, result, dwcb,
                                         dt_p, dlon_p, dlat_p, dw, db, 3, 3, 0);
    fused_kernel<<<fg, 256, 0, stream>>>(T1, T0, u, v, q, result, dwcb,
                                         dt_p, dlon_p, dlat_p, dw, db, 6, 3, 0);
    fused_kernel<<<fg, 256, 0, stream>>>(T0, T1, u, v, q, result, dwcb,
                                         dt_p, dlon_p, dlat_p, dw, db, 9, 3, 0);
    fused_kernel<<<fg, 256, 0, stream>>>(T1, T0, u, v, q, result, dwcb,
                                         dt_p, dlon_p, dlat_p, dw, db, 12, 3, 0);
    fused_kernel<<<fg, 256, 0, stream>>>(T0, T1, u, v, q, result, dwcb,
                                         dt_p, dlon_p, dlat_p, dw, db, 15, 3, 0);
    fused_kernel<<<fg, 256, 0, stream>>>(T1, T0, u, v, q, result, dwcb,
                                         dt_p, dlon_p, dlat_p, dw, db, 18, 2, 2);

    up_kernel<<<dim3(nbp, 8), 256, 0, stream>>>(dwcb, W_up, b_up, out);
}

// Round 7
// 132.752 us; speedup vs baseline: 6.1256x; 2.8979x over previous
//
#include <hip/hip_runtime.h>

#define HH 181
#define WW 360
#define NPIX (HH*WW)        // 65160
#define NCH 16
#define NHID 256
#define NPIX16 (NCH*NPIX)   // 1042560
#define NG4 (NPIX16/4)      // 260640 4-wide groups (exact)
#define GPR (WW/4)          // 90 groups per row
#define GPC (NPIX/4)        // 16290 groups per channel
#define EPITOL 1e-5f
#define NTERMS 19

// K0: transpose W_down (16,256) -> (256,16); zero the early-stop flags.
__global__ __launch_bounds__(256) void tr_kernel(const float* __restrict__ Wd,
                                                 float* __restrict__ WdT,
                                                 unsigned* __restrict__ flags) {
    int i = blockIdx.x * 256 + threadIdx.x;
    if (blockIdx.x == 0 && threadIdx.x < 64) flags[threadIdx.x] = 0u;
    if (i < NCH * NHID) {
        int o = i / NHID, c = i - o * NHID;
        WdT[c * NCH + o] = Wd[i];
    }
}

// K1: q[o,pix] = sum_c WdT[c,o] * hidden[c,pix] + b_down[o]
__global__ __launch_bounds__(256) void down_kernel(const float* __restrict__ hid,
                                                   const float* __restrict__ WdT,
                                                   const float* __restrict__ b_down,
                                                   float* __restrict__ q) {
    int pix = blockIdx.x * 256 + threadIdx.x;
    if (pix >= NPIX) return;
    float acc[NCH];
#pragma unroll
    for (int o = 0; o < NCH; ++o) acc[o] = b_down[o];
#pragma unroll 8
    for (int c = 0; c < NHID; ++c) {
        float hv = hid[c * NPIX + pix];
#pragma unroll
        for (int o = 0; o < NCH; ++o) acc[o] += WdT[c * NCH + o] * hv;
    }
#pragma unroll
    for (int o = 0; o < NCH; ++o) q[o * NPIX + pix] = acc[o];
}

// K2 (x20): one upwind pass, 4 consecutive w per thread, all-float4 traffic.
// k=0: term0 = result = rhs(q).  k>=1: nt = rhs(term)*dt/(k+1); term=nt;
// result += nt; block-max -> plain flag store. Pass k>=2 skips if pass k-1
// saw max|nt| < tol everywhere (flags[k-1]==0) -> cascading early stop.
__global__ __launch_bounds__(256) void pass_kernel(
        const float* __restrict__ tin,
        float* __restrict__ tout,
        const float* __restrict__ u,
        const float* __restrict__ v,
        float* __restrict__ result,
        const float* __restrict__ dt_p,
        const float* __restrict__ dlon_p,
        const float* __restrict__ dlat_p,
        unsigned* __restrict__ flags,
        int k) {
    if (k >= 2) {
        if (flags[k - 1] == 0u) return;   // uniform: whole grid skips together
    }
    const float cp0 = -2.0f/60.0f, cp1 = 15.0f/60.0f, cp2 = -60.0f/60.0f,
                cp3 = 20.0f/60.0f, cp4 = 30.0f/60.0f, cp5 = -3.0f/60.0f;
    const float cn0 =  3.0f/60.0f, cn1 = -30.0f/60.0f, cn2 = -20.0f/60.0f,
                cn3 = 60.0f/60.0f, cn4 = -15.0f/60.0f, cn5 =  2.0f/60.0f;

    const int g4 = blockIdx.x * 256 + threadIdx.x;
    float m = 0.0f;
    if (g4 < NG4) {
        const float inv_dlon = 1.0f / dlon_p[0];
        const float inv_dlat = 1.0f / dlat_p[0];
        const float scale = (k == 0) ? 1.0f : dt_p[0] / (float)(k + 1);

        const int ch  = g4 / GPC;
        const int rem = g4 - ch * GPC;
        const int h   = rem / GPR;
        const int bi  = rem - h * GPR;     // float4 block index in row, 0..89
        const int w0  = bi * 4;

        const float* base = tin + ch * NPIX;
        // lon window: cols w0-4 .. w0+7 as 3 aligned float4 (cyclic by block)
        const float4* rowv = (const float4*)(base + h * WW);
        float4 Af = rowv[bi == 0 ? GPR - 1 : bi - 1];
        float4 Bf = rowv[bi];
        float4 Cf = rowv[bi == GPR - 1 ? 0 : bi + 1];
        float Wn[12] = {Af.x, Af.y, Af.z, Af.w, Bf.x, Bf.y, Bf.z, Bf.w,
                        Cf.x, Cf.y, Cf.z, Cf.w};
        // lat taps: rows h-3..h+3 (pole mirror -> flipped col base, still x4-aligned)
        const int wf0 = (w0 >= WW / 2) ? (w0 - WW / 2) : (w0 + WW / 2);
        float S[7][4];
#pragma unroll
        for (int d = 0; d < 7; ++d) {
            int rr = h + d - 3;
            int cb = w0;
            if (rr < 0)           { rr = -1 - rr;        cb = wf0; }
            else if (rr > HH - 1) { rr = 2*HH - 1 - rr;  cb = wf0; }
            float4 t = *(const float4*)(base + rr * WW + cb);
            S[d][0] = t.x; S[d][1] = t.y; S[d][2] = t.z; S[d][3] = t.w;
        }
        const int gi = ch * NPIX + h * WW + w0;
        float4 Uf = *(const float4*)(u + gi);
        float4 Vf = *(const float4*)(v + gi);
        const float Ua[4] = {Uf.x, Uf.y, Uf.z, Uf.w};
        const float Va[4] = {Vf.x, Vf.y, Vf.z, Vf.w};

        float o4[4];
#pragma unroll
        for (int j = 0; j < 4; ++j) {
            // point w0+j: Wn[4+j] is offset 0; taps -3..+2 (pos) / -2..+3 (neg)
            float dpl = cp0*Wn[j+1] + cp1*Wn[j+2] + cp2*Wn[j+3]
                      + cp3*Wn[j+4] + cp4*Wn[j+5] + cp5*Wn[j+6];
            float dnl = cn0*Wn[j+2] + cn1*Wn[j+3] + cn2*Wn[j+4]
                      + cn3*Wn[j+5] + cn4*Wn[j+6] + cn5*Wn[j+7];
            float dpa = cp0*S[0][j] + cp1*S[1][j] + cp2*S[2][j]
                      + cp3*S[3][j] + cp4*S[4][j] + cp5*S[5][j];
            float dna = cn0*S[1][j] + cn1*S[2][j] + cn2*S[3][j]
                      + cn3*S[4][j] + cn4*S[5][j] + cn5*S[6][j];
            float uu = Ua[j], vv = Va[j];
            float nt = (-uu * ((uu > 0.0f ? dpl : dnl) * inv_dlon)
                        -vv * ((vv > 0.0f ? dpa : dna) * inv_dlat)) * scale;
            o4[j] = nt;
            m = fmaxf(m, fabsf(nt));
        }
        *(float4*)(tout + gi) = make_float4(o4[0], o4[1], o4[2], o4[3]);
        if (k == 0) {
            *(float4*)(result + gi) = make_float4(o4[0], o4[1], o4[2], o4[3]);
        } else {
            float4 R = *(const float4*)(result + gi);
            R.x += o4[0]; R.y += o4[1]; R.z += o4[2]; R.w += o4[3];
            *(float4*)(result + gi) = R;
        }
    }
    if (k >= 1 && k < NTERMS) {   // flags[19] never read; flags[0] never read
        __shared__ float wmax[4];
#pragma unroll
        for (int s = 32; s >= 1; s >>= 1) m = fmaxf(m, __shfl_xor(m, s));
        if ((threadIdx.x & 63) == 0) wmax[threadIdx.x >> 6] = m;
        __syncthreads();
        if (threadIdx.x == 0) {
            float bm = fmaxf(fmaxf(wmax[0], wmax[1]), fmaxf(wmax[2], wmax[3]));
            if (bm >= EPITOL) flags[k] = 1u;   // plain store, no atomic
        }
    }
}

// K3: out[c,pix] = sum_o W_up[c,o]*dwc[o,pix] + b_up[c], with dwc computed
// inline: dwc = (q + result*dt)*dw[o] + db[o]. 8 chunks of 32 channels.
__global__ __launch_bounds__(256) void up_kernel(const float* __restrict__ q,
                                                 const float* __restrict__ result,
                                                 const float* __restrict__ dt_p,
                                                 const float* __restrict__ dw,
                                                 const float* __restrict__ db,
                                                 const float* __restrict__ Wu,
                                                 const float* __restrict__ b_up,
                                                 float* __restrict__ out) {
    int pix = blockIdx.x * 256 + threadIdx.x;
    if (pix >= NPIX) return;
    const float dt = dt_p[0];
    int c0 = blockIdx.y * 32;
    float d[NCH];
#pragma unroll
    for (int o = 0; o < NCH; ++o) {
        int g = o * NPIX + pix;
        d[o] = (q[g] + result[g] * dt) * dw[o] + db[o];
    }
#pragma unroll 4
    for (int cc = 0; cc < 32; ++cc) {
        int c = c0 + cc;
        float a = b_up[c];
#pragma unroll
        for (int o = 0; o < NCH; ++o) a += Wu[c * NCH + o] * d[o];
        out[c * NPIX + pix] = a;
    }
}

extern "C" void kernel_launch(void* const* d_in, const int* in_sizes, int n_in,
                              void* d_out, int out_size, void* d_ws, size_t ws_size,
                              hipStream_t stream) {
    const float* hidden = (const float*)d_in[0];   // (1,256,181,360)
    const float* u      = (const float*)d_in[1];   // (1,16,181,360)
    const float* v      = (const float*)d_in[2];   // (1,16,181,360)
    const float* dt_p   = (const float*)d_in[3];   // scalar
    const float* dlat_p = (const float*)d_in[4];   // scalar
    const float* dlon_p = (const float*)d_in[5];   // scalar
    const float* W_down = (const float*)d_in[6];   // (16,256)
    const float* b_down = (const float*)d_in[7];   // (16,)
    const float* dw     = (const float*)d_in[8];   // (16,)
    const float* db     = (const float*)d_in[9];   // (16,)
    const float* W_up   = (const float*)d_in[10];  // (256,16)
    const float* b_up   = (const float*)d_in[11];  // (256,)
    float* out = (float*)d_out;

    float* ws = (float*)d_ws;
    float* q      = ws;
    float* t0     = ws + (size_t)NPIX16;
    float* t1     = ws + (size_t)2 * NPIX16;
    float* result = ws + (size_t)3 * NPIX16;
    float* WdT    = ws + (size_t)4 * NPIX16;
    unsigned* flags = (unsigned*)(ws + (size_t)4 * NPIX16 + NCH * NHID);

    const int nbp = (NPIX + 255) / 256;   // 255
    const int nbg = (NG4 + 255) / 256;    // 1019

    tr_kernel<<<(NCH * NHID + 255) / 256, 256, 0, stream>>>(W_down, WdT, flags);
    down_kernel<<<nbp, 256, 0, stream>>>(hidden, WdT, b_down, q);

    // pass 0 (F_n) + passes 1..19, ping-ponging term buffers
    pass_kernel<<<nbg, 256, 0, stream>>>(q, t0, u, v, result,
                                         dt_p, dlon_p, dlat_p, flags, 0);
    for (int k = 1; k <= NTERMS; ++k) {
        float* tin  = (k & 1) ? t0 : t1;
        float* tout = (k & 1) ? t1 : t0;
        pass_kernel<<<nbg, 256, 0, stream>>>(tin, tout, u, v, result,
                                             dt_p, dlon_p, dlat_p, flags, k);
    }

    up_kernel<<<dim3(nbp, 8), 256, 0, stream>>>(q, result, dt_p, dw, db,
                                                W_up, b_up, out);
}